// Round 9
// baseline (632.880 us; speedup 1.0000x reference)
//
#include <hip/hip_runtime.h>
#include <hip/hip_bf16.h>
#include <hip/hip_cooperative_groups.h>

namespace cg = cooperative_groups;

// HierarchicalAttention: B=4,T=50,D=512, SRC=400, SENTS=16, WORDS=40.
// Primary path: ONE cooperative kernel, 5 phases with grid.sync() between them
// (phase bodies equivalent to the proven R7 5-kernel pipeline, 153.3us) —
// eliminates 4 serialized dispatch boundaries and yields one aggregate
// counter row for the whole pipeline.
// Fallback path (cooperative launch unavailable/fails): the R7 5-kernel
// pipeline itself, byte-identical.

#define B_    4
#define T_    50
#define D_    512
#define SRC_  400
#define SENTS_ 16
#define WORDS_ 40
#define NW_   640      // SENTS*WORDS
#define NMEM_ 1040     // SRC + NW
#define NK_   1056     // NMEM padded to 32*33 for MFMA K-loop
#define NJOB_ 1056     // NMEM + SENTS (score jobs per batch)

#define C2L2E 2.8853900817779268f   // 2*log2(e): x -> exp2(C2L2E*x) = exp(2x)

typedef unsigned short ushort_t;
using s8v = __attribute__((ext_vector_type(8))) short;   // 8 bf16 (4 VGPRs)
using f4v = __attribute__((ext_vector_type(4))) float;   // MFMA accumulator

// ---- workspace layout ----
// f32 region (float offsets):
#define OFF_WQ_WORD 0
#define OFF_WQ_SENT 102400
#define OFF_WQ_PASS 204800
#define OFF_UH_SRC  307200
#define OFF_UH_WORD 1126400
#define OFF_UH_SENT 2437120
#define OFF_SC_SRC  2469888
#define OFF_SC_WORD 2549888
#define OFF_SC_SENT 2677888
// bf16 regions (byte offsets):
#define P_BYTE_OFF  10724352ull   // P[b][64][1056]  bf16 = 540672 B
#define MT_BYTE_OFF 11265024ull   // Mt[b][512][1056] bf16 = 4325376 B
#define WT_BYTE_OFF 15590400ull   // Wt[6][512][512] bf16 = 3145728 B

__device__ __forceinline__ ushort_t f2b(float f) {
    __hip_bfloat16 h = __float2bfloat16(f);   // RNE
    return *(ushort_t*)&h;
}

// =======================================================================
// Fused cooperative kernel. Shared 8.25KB buffer reused per phase.
// =======================================================================
__global__ __launch_bounds__(256, 4) void fused_all(
    const float* __restrict__ source, const float* __restrict__ src_bank,
    const float* __restrict__ qa_sent_bank, const float* __restrict__ qa_word_bank,
    const float* __restrict__ w0, const float* __restrict__ w1,
    const float* __restrict__ w2, const float* __restrict__ w3,
    const float* __restrict__ w4, const float* __restrict__ w5,
    const float* __restrict__ bq_word, const float* __restrict__ bq_sent,
    const float* __restrict__ bq_pass,
    const float* __restrict__ v_word, const float* __restrict__ v_sent,
    const float* __restrict__ v_pass,
    const int* __restrict__ src_lengths, const int* __restrict__ qa_word_lengths,
    float* __restrict__ wsf, ushort_t* __restrict__ P,
    ushort_t* __restrict__ mt, ushort_t* __restrict__ wt,
    float* __restrict__ out)
{
    __shared__ __align__(16) char smem[8448];
    cg::grid_group gg = cg::this_grid();
    const int bid = blockIdx.x, gsz = gridDim.x;
    const int tid = threadIdx.x;
    const int lane = tid & 63, wv = tid >> 6;

    // ---------------- P0: transposes (3648 jobs) ----------------
    {
        float (*tile)[33] = (float(*)[33])smem;
        int tx = tid & 31, ty = tid >> 5;
        for (int job = bid; job < 3648; job += gsz) {
            if (job < 1536) {
                int z = job >> 8, r = job & 255;
                int n0 = (r & 15) * 32, k0 = (r >> 4) * 32;
                const float* W;
                switch (z) {
                    case 0: W = w0; break; case 1: W = w1; break; case 2: W = w2; break;
                    case 3: W = w3; break; case 4: W = w4; break; default: W = w5; break;
                }
                ushort_t* Wt = wt + z * (D_ * D_);
#pragma unroll
                for (int a = 0; a < 4; ++a)
                    tile[ty + a * 8][tx] = W[(k0 + ty + a * 8) * D_ + n0 + tx];
                __syncthreads();
#pragma unroll
                for (int a = 0; a < 4; ++a)
                    Wt[(n0 + ty + a * 8) * D_ + k0 + tx] = f2b(tile[tx][ty + a * 8]);
            } else {
                int tb = job - 1536;
                int b = tb / 528, r = tb - b * 528;
                int s0 = (r % 33) * 32, d0 = (r / 33) * 32;
#pragma unroll
                for (int a = 0; a < 4; ++a) {
                    int s = s0 + ty + a * 8;
                    float val = 0.f;
                    if (s < SRC_) {
                        val = src_bank[(s * B_ + b) * D_ + d0 + tx];
                    } else if (s < NMEM_) {
                        int j = s - SRC_; int se = j / WORDS_; int wd = j - se * WORDS_;
                        val = qa_word_bank[((wd * B_ + b) * SENTS_ + se) * D_ + d0 + tx];
                    }
                    tile[ty + a * 8][tx] = val;
                }
                __syncthreads();
                ushort_t* base = mt + (size_t)b * D_ * NK_;
#pragma unroll
                for (int a = 0; a < 4; ++a) {
                    int d = d0 + ty + a * 8;
                    base[(size_t)d * NK_ + s0 + tx] = f2b(tile[tx][ty + a * 8]);
                }
            }
            __syncthreads();   // tile reuse guard between jobs
        }
    }
    __threadfence();
    gg.sync();

    // ---------------- P1: projections via bf16 MFMA (624 jobs) ----------------
    {
        short* At = (short*)smem;
        short* Bt = (short*)(smem + 4096);
        int quad = lane >> 4, l16 = lane & 15;
        int sm = tid >> 2, koff = (tid & 3) * 8;
        for (int job = bid; job < 624; job += gsz) {
            int z, rem;
            if (job < 96)       { z = job >> 5; rem = job & 31; }
            else if (job < 416) { z = 3; rem = job - 96; }
            else if (job < 616) { z = 4; rem = job - 416; }
            else                { z = 5; rem = job - 616; }
            int by = rem >> 3, bx = rem & 7;
            int M, atype; const float* bias; float* C;
            switch (z) {
                case 0: M = 200;  atype = 0; bias = bq_word; C = wsf + OFF_WQ_WORD; break;
                case 1: M = 200;  atype = 0; bias = bq_sent; C = wsf + OFF_WQ_SENT; break;
                case 2: M = 200;  atype = 0; bias = bq_pass; C = wsf + OFF_WQ_PASS; break;
                case 3: M = 2560; atype = 1; bias = nullptr; C = wsf + OFF_UH_WORD; break;
                case 4: M = 1600; atype = 2; bias = nullptr; C = wsf + OFF_UH_SRC;  break;
                default: M = 64;  atype = 3; bias = nullptr; C = wsf + OFF_UH_SENT; break;
            }
            int m0 = by * 64, n0 = bx * 64;
            const ushort_t* W = wt + z * (D_ * D_);

            const float* arow = nullptr;
            {
                int r = m0 + sm;
                if (r < M) {
                    if (atype == 0) arow = source + r * D_;
                    else if (atype == 1) { int b = r / NW_; int j = r - b * NW_;
                                           int se = j / WORDS_; int wd = j - se * WORDS_;
                                           arow = qa_word_bank + ((wd * B_ + b) * SENTS_ + se) * D_; }
                    else if (atype == 2) { int b = r / SRC_; int j = r - b * SRC_;
                                           arow = src_bank + (j * B_ + b) * D_; }
                    else                 { int b = r >> 4; int s2 = r & 15;
                                           arow = qa_sent_bank + (s2 * B_ + b) * D_; }
                }
            }
            const ushort_t* wrow = W + (n0 + sm) * D_;

            auto loadA = [&](float* r, int kk) {
                if (arow) {
                    float4 f0 = *(const float4*)(arow + kk * 32 + koff);
                    float4 f1 = *(const float4*)(arow + kk * 32 + koff + 4);
                    r[0]=f0.x; r[1]=f0.y; r[2]=f0.z; r[3]=f0.w;
                    r[4]=f1.x; r[5]=f1.y; r[6]=f1.z; r[7]=f1.w;
                } else {
#pragma unroll
                    for (int i = 0; i < 8; ++i) r[i] = 0.f;
                }
            };

            f4v acc[4] = { {0.f,0.f,0.f,0.f}, {0.f,0.f,0.f,0.f},
                           {0.f,0.f,0.f,0.f}, {0.f,0.f,0.f,0.f} };
            float a0[8], a1[8];
            int4 w0v, w1v;
            loadA(a0, 0); w0v = *(const int4*)(wrow + 0 * 32 + koff);
            loadA(a1, 1); w1v = *(const int4*)(wrow + 1 * 32 + koff);

            for (int kk = 0; kk < 16; ++kk) {
                union { ushort_t u[8]; int4 v; } pk;
#pragma unroll
                for (int i = 0; i < 8; ++i) pk.u[i] = f2b(a0[i]);
                *(int4*)(At + sm * 32 + koff) = pk.v;
                *(int4*)(Bt + sm * 32 + koff) = w0v;
                __syncthreads();
#pragma unroll
                for (int i = 0; i < 8; ++i) a0[i] = a1[i];
                w0v = w1v;
                if (kk < 14) {
                    loadA(a1, kk + 2);
                    w1v = *(const int4*)(wrow + (kk + 2) * 32 + koff);
                }
                s8v af = *(const s8v*)(At + (wv * 16 + l16) * 32 + quad * 8);
#pragma unroll
                for (int ng = 0; ng < 4; ++ng) {
                    s8v bf = *(const s8v*)(Bt + (ng * 16 + l16) * 32 + quad * 8);
                    acc[ng] = __builtin_amdgcn_mfma_f32_16x16x32_bf16(af, bf, acc[ng], 0, 0, 0);
                }
                __syncthreads();
            }
#pragma unroll
            for (int ng = 0; ng < 4; ++ng) {
                int col = n0 + ng * 16 + l16;
                float bb = bias ? bias[col] : 0.f;
#pragma unroll
                for (int rr = 0; rr < 4; ++rr) {
                    int row = m0 + wv * 16 + quad * 4 + rr;
                    if (row < M) C[row * D_ + col] = (acc[ng][rr] + bb) * C2L2E;
                }
            }
        }
    }
    __threadfence();
    gg.sync();

    // ---------------- P2: scores (21120 wave-fifth jobs, R7 structure) ----------------
    {
        for (int jid = bid * 4 + wv; jid < 21120; jid += gsz * 4) {
            int job = jid / 5, fifth = jid - job * 5;
            int b = job / NJOB_, slot = job - b * NJOB_;
            const float* uh; const float* v; const float* wq; float* outp; int ostride;
            if (slot < SRC_) {
                if (slot >= src_lengths[b]) continue;
                uh = wsf + OFF_UH_SRC + (size_t)(b * SRC_ + slot) * D_;
                v = v_pass; wq = wsf + OFF_WQ_PASS + b * T_ * D_;
                outp = wsf + OFF_SC_SRC + b * T_ * SRC_ + slot; ostride = SRC_;
            } else if (slot < NMEM_) {
                int j = slot - SRC_;
                int se = j / WORDS_; int wd = j - se * WORDS_;
                if (wd >= qa_word_lengths[b * SENTS_ + se]) continue;
                uh = wsf + OFF_UH_WORD + (size_t)(b * NW_ + j) * D_;
                v = v_word; wq = wsf + OFF_WQ_WORD + b * T_ * D_;
                outp = wsf + OFF_SC_WORD + b * T_ * NW_ + j; ostride = NW_;
            } else {
                int s2 = slot - NMEM_;
                uh = wsf + OFF_UH_SENT + (size_t)(b * SENTS_ + s2) * D_;
                v = v_sent; wq = wsf + OFF_WQ_SENT + b * T_ * D_;
                outp = wsf + OFF_SC_SENT + b * T_ * SENTS_ + s2; ostride = SENTS_;
            }
            int d0 = lane * 8;
            float4 u0 = *(const float4*)(uh + d0);
            float4 u1 = *(const float4*)(uh + d0 + 4);
            float uhr[8] = {u0.x, u0.y, u0.z, u0.w, u1.x, u1.y, u1.z, u1.w};
            float4 v0 = *(const float4*)(v + d0);
            float4 v1 = *(const float4*)(v + d0 + 4);
            float vr[8] = {v0.x, v0.y, v0.z, v0.w, v1.x, v1.y, v1.z, v1.w};

            float vs = ((vr[0] + vr[1]) + (vr[2] + vr[3])) + ((vr[4] + vr[5]) + (vr[6] + vr[7]));
#pragma unroll
            for (int off = 32; off > 0; off >>= 1) vs += __shfl_xor(vs, off, 64);

            const float* wqh = wq + (fifth * 10) * D_ + d0;
            int tbase = fifth * 10;
#pragma unroll 1
            for (int g = 0; g < 2; ++g) {
                float a5[5];
#pragma unroll
                for (int u5 = 0; u5 < 5; ++u5) {
                    const float* wr = wqh + (g * 5 + u5) * D_;
                    float4 ww0 = *(const float4*)(wr);
                    float4 ww1 = *(const float4*)(wr + 4);
                    float wrr[8] = {ww0.x, ww0.y, ww0.z, ww0.w, ww1.x, ww1.y, ww1.z, ww1.w};
                    float a = 0.f;
#pragma unroll
                    for (int j = 0; j < 8; ++j) {
                        float e = __builtin_amdgcn_exp2f(wrr[j] + uhr[j]);  // exp(2x)
                        float rc = __builtin_amdgcn_rcpf(e + 1.f);          // sigmoid(-2x)
                        a = fmaf(vr[j], rc, a);
                    }
                    a5[u5] = a;
                }
#pragma unroll
                for (int off = 32; off > 0; off >>= 1) {
#pragma unroll
                    for (int u5 = 0; u5 < 5; ++u5) a5[u5] += __shfl_xor(a5[u5], off, 64);
                }
                if (lane == 0) {
#pragma unroll
                    for (int u5 = 0; u5 < 5; ++u5)
                        outp[(tbase + g * 5 + u5) * ostride] = fmaf(-2.f, a5[u5], vs);
                }
            }
        }
    }
    __threadfence();
    gg.sync();

    // ---------------- P3: hier combine + mask + softmax -> bf16 P (200 jobs) ----------------
    {
        float* p = (float*)smem;
        float* red = (float*)(smem + 4160);
        for (int bt = bid; bt < 200; bt += gsz) {
            int b = bt / T_, t = bt - b * T_;
            const float* sc_src  = wsf + OFF_SC_SRC  + bt * SRC_;
            const float* sc_word = wsf + OFF_SC_WORD + bt * NW_;
            const float* sc_sent = wsf + OFF_SC_SENT + bt * SENTS_;
            int slen = src_lengths[b];
            float mx = -3.0e38f;
            for (int j = tid; j < NMEM_; j += 256) {
                float val;
                if (j < SRC_) {
                    val = (j < slen) ? sc_src[j] : -1e30f;
                } else {
                    int jj = j - SRC_; int se = jj / WORDS_; int wd = jj - se * WORDS_;
                    float raw = sc_word[jj] * sc_sent[se];
                    val = (wd < qa_word_lengths[b * SENTS_ + se]) ? raw : -1e30f;
                }
                p[j] = val;
                mx = fmaxf(mx, val);
            }
#pragma unroll
            for (int off = 32; off > 0; off >>= 1) mx = fmaxf(mx, __shfl_xor(mx, off, 64));
            if (lane == 0) red[wv] = mx;
            __syncthreads();
            mx = fmaxf(fmaxf(red[0], red[1]), fmaxf(red[2], red[3]));
            __syncthreads();
            float lsum = 0.f;
            for (int j = tid; j < NMEM_; j += 256) {
                float e = __expf(p[j] - mx);
                p[j] = e; lsum += e;
            }
#pragma unroll
            for (int off = 32; off > 0; off >>= 1) lsum += __shfl_xor(lsum, off, 64);
            if (lane == 0) red[wv] = lsum;
            __syncthreads();
            float inv = 1.f / (red[0] + red[1] + red[2] + red[3]);
            ushort_t* prow = P + (size_t)(b * 64 + t) * NK_;
            for (int j = tid; j < NK_; j += 256)
                prow[j] = (j < NMEM_) ? f2b(p[j] * inv) : (ushort_t)0;
            __syncthreads();   // p[] reuse guard
        }
    }
    __threadfence();
    gg.sync();

    // ---------------- P4: context GEMM (64 jobs) ----------------
    {
        short* At = (short*)smem;
        short* Bt = (short*)(smem + 4096);
        int quad = lane >> 4, l16 = lane & 15;
        int smA = tid >> 2, koffA = (tid & 3) * 8;
        int smB = tid >> 3, koffB = (tid & 7) * 4;
        for (int j4 = bid; j4 < 64; j4 += gsz) {
            int b = j4 >> 4, n0 = (j4 & 15) * 32;
            const ushort_t* arow = P + (size_t)(b * 64 + smA) * NK_ + koffA;
            const ushort_t* brow = mt + ((size_t)(b * D_ + n0 + smB)) * NK_ + koffB;

            f4v acc[2] = { {0.f,0.f,0.f,0.f}, {0.f,0.f,0.f,0.f} };
            int4 a0 = *(const int4*)(arow);
            int2 b0 = *(const int2*)(brow);
            int4 a1 = *(const int4*)(arow + 32);
            int2 b1 = *(const int2*)(brow + 32);
            int4 a2 = *(const int4*)(arow + 64);
            int2 b2 = *(const int2*)(brow + 64);

            for (int kk = 0; kk < 33; ++kk) {
                *(int4*)(At + smA * 32 + koffA) = a0;
                *(int2*)(Bt + smB * 32 + koffB) = b0;
                __syncthreads();
                a0 = a1; a1 = a2; b0 = b1; b1 = b2;
                if (kk < 30) {
                    a2 = *(const int4*)(arow + (kk + 3) * 32);
                    b2 = *(const int2*)(brow + (kk + 3) * 32);
                }
                s8v af = *(const s8v*)(At + (wv * 16 + l16) * 32 + quad * 8);
#pragma unroll
                for (int ng = 0; ng < 2; ++ng) {
                    s8v bf = *(const s8v*)(Bt + (ng * 16 + l16) * 32 + quad * 8);
                    acc[ng] = __builtin_amdgcn_mfma_f32_16x16x32_bf16(af, bf, acc[ng], 0, 0, 0);
                }
                __syncthreads();
            }
#pragma unroll
            for (int ng = 0; ng < 2; ++ng) {
                int col = n0 + ng * 16 + l16;
#pragma unroll
                for (int rr = 0; rr < 4; ++rr) {
                    int row = wv * 16 + quad * 4 + rr;   // t
                    if (row < T_) out[(size_t)(b * T_ + row) * D_ + col] = acc[ng][rr];
                }
            }
        }
    }
}

// =======================================================================
// Fallback path: R7 5-kernel pipeline (proven 153.3us), byte-identical.
// =======================================================================
__global__ __launch_bounds__(256) void k0f_transpose(
    const float* __restrict__ w0, const float* __restrict__ w1,
    const float* __restrict__ w2, const float* __restrict__ w3,
    const float* __restrict__ w4, const float* __restrict__ w5,
    const float* __restrict__ src_bank, const float* __restrict__ qa_word_bank,
    ushort_t* __restrict__ wt, ushort_t* __restrict__ mt)
{
    __shared__ float tile[32][33];
    int bid = blockIdx.x;
    int tx = threadIdx.x & 31, ty = threadIdx.x >> 5;
    if (bid < 1536) {
        int z = bid >> 8, r = bid & 255;
        int n0 = (r & 15) * 32, k0 = (r >> 4) * 32;
        const float* W;
        switch (z) {
            case 0: W = w0; break; case 1: W = w1; break; case 2: W = w2; break;
            case 3: W = w3; break; case 4: W = w4; break; default: W = w5; break;
        }
        ushort_t* Wt = wt + z * (D_ * D_);
#pragma unroll
        for (int a = 0; a < 4; ++a)
            tile[ty + a * 8][tx] = W[(k0 + ty + a * 8) * D_ + n0 + tx];
        __syncthreads();
#pragma unroll
        for (int a = 0; a < 4; ++a)
            Wt[(n0 + ty + a * 8) * D_ + k0 + tx] = f2b(tile[tx][ty + a * 8]);
    } else {
        int tb = bid - 1536;
        int b = tb / 528, r = tb - b * 528;
        int s0 = (r % 33) * 32, d0 = (r / 33) * 32;
#pragma unroll
        for (int a = 0; a < 4; ++a) {
            int s = s0 + ty + a * 8;
            float val = 0.f;
            if (s < SRC_) {
                val = src_bank[(s * B_ + b) * D_ + d0 + tx];
            } else if (s < NMEM_) {
                int j = s - SRC_; int se = j / WORDS_; int wd = j - se * WORDS_;
                val = qa_word_bank[((wd * B_ + b) * SENTS_ + se) * D_ + d0 + tx];
            }
            tile[ty + a * 8][tx] = val;
        }
        __syncthreads();
        ushort_t* base = mt + (size_t)b * D_ * NK_;
#pragma unroll
        for (int a = 0; a < 4; ++a) {
            int d = d0 + ty + a * 8;
            base[(size_t)d * NK_ + s0 + tx] = f2b(tile[tx][ty + a * 8]);
        }
    }
}

__global__ __launch_bounds__(256) void k1_gemm(
    const float* __restrict__ source, const float* __restrict__ src_bank,
    const float* __restrict__ qa_sent_bank, const float* __restrict__ qa_word_bank,
    const ushort_t* __restrict__ wt,
    const float* __restrict__ bq_word, const float* __restrict__ bq_sent,
    const float* __restrict__ bq_pass,
    float* __restrict__ wsf)
{
    __shared__ short At[64 * 32];
    __shared__ short Bt[64 * 32];
    int bid = blockIdx.x;
    int z, rem;
    if (bid < 96)       { z = bid >> 5; rem = bid & 31; }
    else if (bid < 416) { z = 3; rem = bid - 96; }
    else if (bid < 616) { z = 4; rem = bid - 416; }
    else                { z = 5; rem = bid - 616; }
    int by = rem >> 3, bx = rem & 7;
    int M, atype; const float* bias; float* C;
    switch (z) {
        case 0: M = 200;  atype = 0; bias = bq_word; C = wsf + OFF_WQ_WORD; break;
        case 1: M = 200;  atype = 0; bias = bq_sent; C = wsf + OFF_WQ_SENT; break;
        case 2: M = 200;  atype = 0; bias = bq_pass; C = wsf + OFF_WQ_PASS; break;
        case 3: M = 2560; atype = 1; bias = nullptr; C = wsf + OFF_UH_WORD; break;
        case 4: M = 1600; atype = 2; bias = nullptr; C = wsf + OFF_UH_SRC;  break;
        default: M = 64;  atype = 3; bias = nullptr; C = wsf + OFF_UH_SENT; break;
    }
    int m0 = by * 64, n0 = bx * 64;
    const ushort_t* W = wt + z * (D_ * D_);

    int tid = threadIdx.x;
    int lane = tid & 63, wv = tid >> 6;
    int quad = lane >> 4, l16 = lane & 15;
    int sm = tid >> 2, koff = (tid & 3) * 8;

    const float* arow = nullptr;
    {
        int r = m0 + sm;
        if (r < M) {
            if (atype == 0) arow = source + r * D_;
            else if (atype == 1) { int b = r / NW_; int j = r - b * NW_;
                                   int se = j / WORDS_; int wd = j - se * WORDS_;
                                   arow = qa_word_bank + ((wd * B_ + b) * SENTS_ + se) * D_; }
            else if (atype == 2) { int b = r / SRC_; int j = r - b * SRC_;
                                   arow = src_bank + (j * B_ + b) * D_; }
            else                 { int b = r >> 4; int s2 = r & 15;
                                   arow = qa_sent_bank + (s2 * B_ + b) * D_; }
        }
    }
    const ushort_t* wrow = W + (n0 + sm) * D_;

    auto loadA = [&](float* r, int kk) {
        if (arow) {
            float4 f0 = *(const float4*)(arow + kk * 32 + koff);
            float4 f1 = *(const float4*)(arow + kk * 32 + koff + 4);
            r[0]=f0.x; r[1]=f0.y; r[2]=f0.z; r[3]=f0.w;
            r[4]=f1.x; r[5]=f1.y; r[6]=f1.z; r[7]=f1.w;
        } else {
#pragma unroll
            for (int i = 0; i < 8; ++i) r[i] = 0.f;
        }
    };

    f4v acc[4] = { {0.f,0.f,0.f,0.f}, {0.f,0.f,0.f,0.f},
                   {0.f,0.f,0.f,0.f}, {0.f,0.f,0.f,0.f} };

    float a0[8], a1[8];
    int4 w0v, w1v;
    loadA(a0, 0); w0v = *(const int4*)(wrow + 0 * 32 + koff);
    loadA(a1, 1); w1v = *(const int4*)(wrow + 1 * 32 + koff);

    for (int kk = 0; kk < 16; ++kk) {
        union { ushort_t u[8]; int4 v; } pk;
#pragma unroll
        for (int i = 0; i < 8; ++i) pk.u[i] = f2b(a0[i]);
        *(int4*)(At + sm * 32 + koff) = pk.v;
        *(int4*)(Bt + sm * 32 + koff) = w0v;
        __syncthreads();
#pragma unroll
        for (int i = 0; i < 8; ++i) a0[i] = a1[i];
        w0v = w1v;
        if (kk < 14) {
            loadA(a1, kk + 2);
            w1v = *(const int4*)(wrow + (kk + 2) * 32 + koff);
        }
        s8v af = *(const s8v*)(At + (wv * 16 + l16) * 32 + quad * 8);
#pragma unroll
        for (int ng = 0; ng < 4; ++ng) {
            s8v bf = *(const s8v*)(Bt + (ng * 16 + l16) * 32 + quad * 8);
            acc[ng] = __builtin_amdgcn_mfma_f32_16x16x32_bf16(af, bf, acc[ng], 0, 0, 0);
        }
        __syncthreads();
    }
#pragma unroll
    for (int ng = 0; ng < 4; ++ng) {
        int col = n0 + ng * 16 + l16;
        float bb = bias ? bias[col] : 0.f;
#pragma unroll
        for (int rr = 0; rr < 4; ++rr) {
            int row = m0 + wv * 16 + quad * 4 + rr;
            if (row < M) C[row * D_ + col] = (acc[ng][rr] + bb) * C2L2E;
        }
    }
}

__global__ __launch_bounds__(256) void k2_scores(
    const float* __restrict__ v_word, const float* __restrict__ v_sent,
    const float* __restrict__ v_pass,
    const int* __restrict__ src_lengths, const int* __restrict__ qa_word_lengths,
    float* __restrict__ wsf)
{
    int lane = threadIdx.x & 63;
    int jid = blockIdx.x * 4 + (threadIdx.x >> 6);
    int job = jid / 5, fifth = jid - job * 5;
    int b = job / NJOB_, slot = job - b * NJOB_;
    const float* uh; const float* v; const float* wq; float* out; int ostride;
    if (slot < SRC_) {
        if (slot >= src_lengths[b]) return;
        uh = wsf + OFF_UH_SRC + (size_t)(b * SRC_ + slot) * D_;
        v = v_pass; wq = wsf + OFF_WQ_PASS + b * T_ * D_;
        out = wsf + OFF_SC_SRC + b * T_ * SRC_ + slot; ostride = SRC_;
    } else if (slot < NMEM_) {
        int j = slot - SRC_;
        int se = j / WORDS_; int wd = j - se * WORDS_;
        if (wd >= qa_word_lengths[b * SENTS_ + se]) return;
        uh = wsf + OFF_UH_WORD + (size_t)(b * NW_ + j) * D_;
        v = v_word; wq = wsf + OFF_WQ_WORD + b * T_ * D_;
        out = wsf + OFF_SC_WORD + b * T_ * NW_ + j; ostride = NW_;
    } else {
        int s2 = slot - NMEM_;
        uh = wsf + OFF_UH_SENT + (size_t)(b * SENTS_ + s2) * D_;
        v = v_sent; wq = wsf + OFF_WQ_SENT + b * T_ * D_;
        out = wsf + OFF_SC_SENT + b * T_ * SENTS_ + s2; ostride = SENTS_;
    }
    int d0 = lane * 8;
    float4 u0 = *(const float4*)(uh + d0);
    float4 u1 = *(const float4*)(uh + d0 + 4);
    float uhr[8] = {u0.x, u0.y, u0.z, u0.w, u1.x, u1.y, u1.z, u1.w};
    float4 v0 = *(const float4*)(v + d0);
    float4 v1 = *(const float4*)(v + d0 + 4);
    float vr[8] = {v0.x, v0.y, v0.z, v0.w, v1.x, v1.y, v1.z, v1.w};

    float vs = ((vr[0] + vr[1]) + (vr[2] + vr[3])) + ((vr[4] + vr[5]) + (vr[6] + vr[7]));
#pragma unroll
    for (int off = 32; off > 0; off >>= 1) vs += __shfl_xor(vs, off, 64);

    const float* wqh = wq + (fifth * 10) * D_ + d0;
    int tbase = fifth * 10;
#pragma unroll 1
    for (int g = 0; g < 2; ++g) {
        float a5[5];
#pragma unroll
        for (int u5 = 0; u5 < 5; ++u5) {
            const float* wr = wqh + (g * 5 + u5) * D_;
            float4 w0 = *(const float4*)(wr);
            float4 w1 = *(const float4*)(wr + 4);
            float wrr[8] = {w0.x, w0.y, w0.z, w0.w, w1.x, w1.y, w1.z, w1.w};
            float a = 0.f;
#pragma unroll
            for (int j = 0; j < 8; ++j) {
                float e = __builtin_amdgcn_exp2f(wrr[j] + uhr[j]);
                float r = __builtin_amdgcn_rcpf(e + 1.f);
                a = fmaf(vr[j], r, a);
            }
            a5[u5] = a;
        }
#pragma unroll
        for (int off = 32; off > 0; off >>= 1) {
#pragma unroll
            for (int u5 = 0; u5 < 5; ++u5) a5[u5] += __shfl_xor(a5[u5], off, 64);
        }
        if (lane == 0) {
#pragma unroll
            for (int u5 = 0; u5 < 5; ++u5)
                out[(tbase + g * 5 + u5) * ostride] = fmaf(-2.f, a5[u5], vs);
        }
    }
}

__global__ __launch_bounds__(256) void k3a_softmax(
    const int* __restrict__ src_lengths, const int* __restrict__ qa_word_lengths,
    const float* __restrict__ wsf, ushort_t* __restrict__ P)
{
    __shared__ float p[NMEM_];
    __shared__ float red[4];
    int tid = threadIdx.x, lane = tid & 63, wv = tid >> 6;
    int bt = blockIdx.x, b = bt / T_, t = bt - b * T_;
    const float* sc_src  = wsf + OFF_SC_SRC  + bt * SRC_;
    const float* sc_word = wsf + OFF_SC_WORD + bt * NW_;
    const float* sc_sent = wsf + OFF_SC_SENT + bt * SENTS_;
    int slen = src_lengths[b];
    float mx = -3.0e38f;
    for (int j = tid; j < NMEM_; j += 256) {
        float val;
        if (j < SRC_) {
            val = (j < slen) ? sc_src[j] : -1e30f;
        } else {
            int jj = j - SRC_; int se = jj / WORDS_; int wd = jj - se * WORDS_;
            float raw = sc_word[jj] * sc_sent[se];
            val = (wd < qa_word_lengths[b * SENTS_ + se]) ? raw : -1e30f;
        }
        p[j] = val;
        mx = fmaxf(mx, val);
    }
#pragma unroll
    for (int off = 32; off > 0; off >>= 1) mx = fmaxf(mx, __shfl_xor(mx, off, 64));
    if (lane == 0) red[wv] = mx;
    __syncthreads();
    mx = fmaxf(fmaxf(red[0], red[1]), fmaxf(red[2], red[3]));
    __syncthreads();
    float lsum = 0.f;
    for (int j = tid; j < NMEM_; j += 256) {
        float e = __expf(p[j] - mx);
        p[j] = e; lsum += e;
    }
#pragma unroll
    for (int off = 32; off > 0; off >>= 1) lsum += __shfl_xor(lsum, off, 64);
    if (lane == 0) red[wv] = lsum;
    __syncthreads();
    float inv = 1.f / (red[0] + red[1] + red[2] + red[3]);
    ushort_t* prow = P + (size_t)(b * 64 + t) * NK_;
    for (int j = tid; j < NK_; j += 256)
        prow[j] = (j < NMEM_) ? f2b(p[j] * inv) : (ushort_t)0;
}

__global__ __launch_bounds__(256) void k3c_gemm(
    const ushort_t* __restrict__ P, const ushort_t* __restrict__ Mt,
    float* __restrict__ out)
{
    __shared__ short At[64 * 32];
    __shared__ short Bt[32 * 32];
    int b = blockIdx.y;
    int n0 = blockIdx.x * 32;
    int tid = threadIdx.x;
    int lane = tid & 63, wv = tid >> 6;
    int quad = lane >> 4, l16 = lane & 15;
    int smA = tid >> 2, koffA = (tid & 3) * 8;
    int smB = tid >> 3, koffB = (tid & 7) * 4;

    const ushort_t* arow = P + (size_t)(b * 64 + smA) * NK_ + koffA;
    const ushort_t* brow = Mt + ((size_t)(b * D_ + n0 + smB)) * NK_ + koffB;

    f4v acc[2] = { {0.f,0.f,0.f,0.f}, {0.f,0.f,0.f,0.f} };

    int4 a0 = *(const int4*)(arow);
    int2 b0 = *(const int2*)(brow);
    int4 a1 = *(const int4*)(arow + 32);
    int2 b1 = *(const int2*)(brow + 32);
    int4 a2 = *(const int4*)(arow + 64);
    int2 b2 = *(const int2*)(brow + 64);

    for (int kk = 0; kk < 33; ++kk) {
        *(int4*)(At + smA * 32 + koffA) = a0;
        *(int2*)(Bt + smB * 32 + koffB) = b0;
        __syncthreads();
        a0 = a1; a1 = a2; b0 = b1; b1 = b2;
        if (kk < 30) {
            a2 = *(const int4*)(arow + (kk + 3) * 32);
            b2 = *(const int2*)(brow + (kk + 3) * 32);
        }
        s8v af = *(const s8v*)(At + (wv * 16 + l16) * 32 + quad * 8);
#pragma unroll
        for (int ng = 0; ng < 2; ++ng) {
            s8v bf = *(const s8v*)(Bt + (ng * 16 + l16) * 32 + quad * 8);
            acc[ng] = __builtin_amdgcn_mfma_f32_16x16x32_bf16(af, bf, acc[ng], 0, 0, 0);
        }
        __syncthreads();
    }
#pragma unroll
    for (int ng = 0; ng < 2; ++ng) {
        int col = n0 + ng * 16 + l16;
#pragma unroll
        for (int rr = 0; rr < 4; ++rr) {
            int row = wv * 16 + quad * 4 + rr;
            if (row < T_) out[(size_t)(b * T_ + row) * D_ + col] = acc[ng][rr];
        }
    }
}

extern "C" void kernel_launch(void* const* d_in, const int* in_sizes, int n_in,
                              void* d_out, int out_size, void* d_ws, size_t ws_size,
                              hipStream_t stream)
{
    (void)in_sizes; (void)n_in; (void)out_size; (void)ws_size;
    const float* source          = (const float*)d_in[0];
    const float* src_bank        = (const float*)d_in[1];
    const int*   src_lengths     = (const int*)d_in[2];
    const float* qa_sent_bank    = (const float*)d_in[3];
    /* d_in[4] qa_sent_lengths unused (matches reference) */
    const float* qa_word_bank    = (const float*)d_in[5];
    const int*   qa_word_lengths = (const int*)d_in[6];
    const float* Wq_word = (const float*)d_in[7];
    const float* bq_word = (const float*)d_in[8];
    const float* Uc_word = (const float*)d_in[9];
    const float* v_word  = (const float*)d_in[10];
    const float* Wq_sent = (const float*)d_in[11];
    const float* bq_sent = (const float*)d_in[12];
    const float* Uc_sent = (const float*)d_in[13];
    const float* v_sent  = (const float*)d_in[14];
    const float* Wq_pass = (const float*)d_in[15];
    const float* bq_pass = (const float*)d_in[16];
    const float* Uc_pass = (const float*)d_in[17];
    const float* v_pass  = (const float*)d_in[18];

    float* wsf = (float*)d_ws;
    ushort_t* Pb  = (ushort_t*)((char*)d_ws + P_BYTE_OFF);
    ushort_t* mt  = (ushort_t*)((char*)d_ws + MT_BYTE_OFF);
    ushort_t* wt  = (ushort_t*)((char*)d_ws + WT_BYTE_OFF);
    float* out = (float*)d_out;

    // ---- primary: single cooperative kernel ----
    int nb = 0;
    hipError_t qe = hipOccupancyMaxActiveBlocksPerMultiprocessor(&nb, fused_all, 256, 0);
    if (qe == hipSuccess && nb > 0) {
        int grid = nb * 256;            // nb blocks/CU x 256 CUs (co-residency bound)
        if (grid > 2048) grid = 2048;
        void* args[] = {
            (void*)&source, (void*)&src_bank, (void*)&qa_sent_bank, (void*)&qa_word_bank,
            (void*)&Wq_word, (void*)&Wq_sent, (void*)&Wq_pass,
            (void*)&Uc_word, (void*)&Uc_pass, (void*)&Uc_sent,
            (void*)&bq_word, (void*)&bq_sent, (void*)&bq_pass,
            (void*)&v_word, (void*)&v_sent, (void*)&v_pass,
            (void*)&src_lengths, (void*)&qa_word_lengths,
            (void*)&wsf, (void*)&Pb, (void*)&mt, (void*)&wt, (void*)&out
        };
        hipError_t le = hipLaunchCooperativeKernel((void*)fused_all, dim3(grid),
                                                   dim3(256), args, 0, stream);
        if (le == hipSuccess) return;
    }

    // ---- fallback: R7 5-kernel pipeline (proven 153.3us) ----
    k0f_transpose<<<dim3(3648), dim3(256), 0, stream>>>(
        Wq_word, Wq_sent, Wq_pass, Uc_word, Uc_pass, Uc_sent,
        src_bank, qa_word_bank, wt, mt);
    k1_gemm<<<dim3(624), dim3(256), 0, stream>>>(
        source, src_bank, qa_sent_bank, qa_word_bank, wt,
        bq_word, bq_sent, bq_pass, wsf);
    k2_scores<<<dim3(5280), dim3(256), 0, stream>>>(
        v_word, v_sent, v_pass, src_lengths, qa_word_lengths, wsf);
    k3a_softmax<<<dim3(200), dim3(256), 0, stream>>>(src_lengths, qa_word_lengths, wsf, Pb);
    k3c_gemm<<<dim3(16, 4), dim3(256), 0, stream>>>(Pb, mt, out);
}

// Round 10
// 154.064 us; speedup vs baseline: 4.1079x; 4.1079x over previous
//
#include <hip/hip_runtime.h>
#include <hip/hip_bf16.h>

// HierarchicalAttention: B=4,T=50,D=512, SRC=400, SENTS=16, WORDS=40.
// 4-launch pipeline (R9 killed grid-sync fusion; this merges by dependency):
//   kA   projections via bf16 MFMA with INLINE weight transpose (no Wt buffer,
//        no k0f weight pass) + bank->Mt transpose blocks in the same launch
//        (Mt needed only by k3c; transpose blocks overlap the GEMM blocks)
//   k2   tanh scores — R7's 5280-block wave-fifth split (proven)
//   k3a  hier combine + mask + softmax -> bf16 P (proven)
//   k3c  MFMA context GEMM, depth-3 register prefetch (proven)

#define B_    4
#define T_    50
#define D_    512
#define SRC_  400
#define SENTS_ 16
#define WORDS_ 40
#define NW_   640      // SENTS*WORDS
#define NMEM_ 1040     // SRC + NW
#define NK_   1056     // NMEM padded to 32*33 for MFMA K-loop
#define NJOB_ 1056     // NMEM + SENTS (score jobs per batch)

#define C2L2E 2.8853900817779268f   // 2*log2(e): x -> exp2(C2L2E*x) = exp(2x)

typedef unsigned short ushort_t;
using s8v = __attribute__((ext_vector_type(8))) short;   // 8 bf16 (4 VGPRs)
using f4v = __attribute__((ext_vector_type(4))) float;   // MFMA accumulator

// ---- workspace layout ----
// f32 region (float offsets):
#define OFF_WQ_WORD 0
#define OFF_WQ_SENT 102400
#define OFF_WQ_PASS 204800
#define OFF_UH_SRC  307200
#define OFF_UH_WORD 1126400
#define OFF_UH_SENT 2437120
#define OFF_SC_SRC  2469888
#define OFF_SC_WORD 2549888
#define OFF_SC_SENT 2677888
// bf16 regions (byte offsets):
#define P_BYTE_OFF  10724352ull   // P[b][64][1056]  bf16 = 540672 B
#define MT_BYTE_OFF 11265024ull   // Mt[b][512][1056] bf16 = 4325376 B

__device__ __forceinline__ ushort_t f2b(float f) {
    __hip_bfloat16 h = __float2bfloat16(f);   // RNE
    return *(ushort_t*)&h;
}

// ---------------- kA: projections (inline W transpose) + bank->Mt ----------------
// bid < 624: compact GEMM blocks (z0-2: 32 each M=200, z3: 320 M=2560,
//   z4: 200 M=1600, z5: 8 M=64). Block tile 64x64, K=512 in 16 steps. Per step,
//   the W[k][n] f32 tile is staged to LDS (Wtmp, col-swizzled), transposed +
//   converted to bf16 Bt in-block; A rows converted to At. 2 barriers/step;
//   A and W global loads register-prefetched 2 steps ahead. Numerically
//   identical to the k0f+k1 path (same RNE conversion point).
// bid >= 624: bank transpose blocks -> Mt[b][d][s] bf16 (needed only by k3c).
__global__ __launch_bounds__(256) void kA(
    const float* __restrict__ source, const float* __restrict__ src_bank,
    const float* __restrict__ qa_sent_bank, const float* __restrict__ qa_word_bank,
    const float* __restrict__ w0, const float* __restrict__ w1,
    const float* __restrict__ w2, const float* __restrict__ w3,
    const float* __restrict__ w4, const float* __restrict__ w5,
    const float* __restrict__ bq_word, const float* __restrict__ bq_sent,
    const float* __restrict__ bq_pass,
    float* __restrict__ wsf, ushort_t* __restrict__ mt)
{
    __shared__ float smemf[4224];   // GEMM: At[0,1024) Bt[1024,2048) Wtmp[2048,4224)
    int bid = blockIdx.x;
    int tid = threadIdx.x;

    if (bid >= 624) {
        // ---- bank transpose -> Mt ----
        int tb = bid - 624;
        int b = tb / 528, r = tb - b * 528;
        int s0 = (r % 33) * 32, d0 = (r / 33) * 32;
        float (*tile)[33] = (float(*)[33])smemf;
        int tx = tid & 31, ty = tid >> 5;
#pragma unroll
        for (int a = 0; a < 4; ++a) {
            int s = s0 + ty + a * 8;
            float val = 0.f;
            if (s < SRC_) {
                val = src_bank[(s * B_ + b) * D_ + d0 + tx];
            } else if (s < NMEM_) {
                int j = s - SRC_; int se = j / WORDS_; int wd = j - se * WORDS_;
                val = qa_word_bank[((wd * B_ + b) * SENTS_ + se) * D_ + d0 + tx];
            }
            tile[ty + a * 8][tx] = val;
        }
        __syncthreads();
        ushort_t* base = mt + (size_t)b * D_ * NK_;
#pragma unroll
        for (int a = 0; a < 4; ++a) {
            int d = d0 + ty + a * 8;
            base[(size_t)d * NK_ + s0 + tx] = f2b(tile[tx][ty + a * 8]);
        }
        return;
    }

    // ---- GEMM with inline weight transpose ----
    int z, rem;
    if (bid < 96)       { z = bid >> 5; rem = bid & 31; }
    else if (bid < 416) { z = 3; rem = bid - 96; }
    else if (bid < 616) { z = 4; rem = bid - 416; }
    else                { z = 5; rem = bid - 616; }
    int by = rem >> 3, bx = rem & 7;
    int M, atype; const float* bias; const float* W; float* C;
    switch (z) {
        case 0: M = 200;  atype = 0; bias = bq_word; W = w0; C = wsf + OFF_WQ_WORD; break;
        case 1: M = 200;  atype = 0; bias = bq_sent; W = w1; C = wsf + OFF_WQ_SENT; break;
        case 2: M = 200;  atype = 0; bias = bq_pass; W = w2; C = wsf + OFF_WQ_PASS; break;
        case 3: M = 2560; atype = 1; bias = nullptr; W = w3; C = wsf + OFF_UH_WORD; break;
        case 4: M = 1600; atype = 2; bias = nullptr; W = w4; C = wsf + OFF_UH_SRC;  break;
        default: M = 64;  atype = 3; bias = nullptr; W = w5; C = wsf + OFF_UH_SENT; break;
    }
    int m0 = by * 64, n0 = bx * 64;

    int lane = tid & 63, wvx = tid >> 6, quad = lane >> 4, l16 = lane & 15;
    int sm = tid >> 2, koff = (tid & 3) * 8;            // A staging: row, 8-chunk
    int rW = tid >> 3, cW = (tid & 7) * 8;              // W staging: k-row, 8 n-cols
    int rWs = rW * 68 + (cW ^ (((rW >> 3) & 3) << 4));  // swizzled Wtmp write base
    int nB = tid >> 2, kB8 = (tid & 3) * 8;             // Bt builder: n-row, 8 k
    int colp = nB ^ (((kB8 >> 3) & 3) << 4);            // swizzled Wtmp read col

    short* At = (short*)smemf;
    short* Bt = (short*)(smemf + 1024);
    float* Wtmp = smemf + 2048;                         // [32][68] f32, col-swizzled

    // A-row gather base (row -> global f32 pointer per segment type)
    const float* arow = nullptr;
    {
        int rr = m0 + sm;
        if (rr < M) {
            if (atype == 0) arow = source + rr * D_;
            else if (atype == 1) { int b = rr / NW_; int j = rr - b * NW_;
                                   int se = j / WORDS_; int wd = j - se * WORDS_;
                                   arow = qa_word_bank + ((wd * B_ + b) * SENTS_ + se) * D_; }
            else if (atype == 2) { int b = rr / SRC_; int j = rr - b * SRC_;
                                   arow = src_bank + (j * B_ + b) * D_; }
            else                 { int b = rr >> 4; int s2 = rr & 15;
                                   arow = qa_sent_bank + (s2 * B_ + b) * D_; }
        }
    }
    const float* wbase = W + n0 + cW;

    auto loadA = [&](float* r, int kk) {
        if (arow) {
            float4 f0 = *(const float4*)(arow + kk * 32 + koff);
            float4 f1 = *(const float4*)(arow + kk * 32 + koff + 4);
            r[0]=f0.x; r[1]=f0.y; r[2]=f0.z; r[3]=f0.w;
            r[4]=f1.x; r[5]=f1.y; r[6]=f1.z; r[7]=f1.w;
        } else {
#pragma unroll
            for (int i = 0; i < 8; ++i) r[i] = 0.f;
        }
    };
    auto loadW = [&](float* r, int kk) {
        const float* p = wbase + (kk * 32 + rW) * D_;
        float4 f0 = *(const float4*)p;
        float4 f1 = *(const float4*)(p + 4);
        r[0]=f0.x; r[1]=f0.y; r[2]=f0.z; r[3]=f0.w;
        r[4]=f1.x; r[5]=f1.y; r[6]=f1.z; r[7]=f1.w;
    };
    auto storeWtmp = [&](const float* r) {
        *(float4*)(Wtmp + rWs)     = float4{r[0], r[1], r[2], r[3]};
        *(float4*)(Wtmp + rWs + 4) = float4{r[4], r[5], r[6], r[7]};
    };
    auto storeAt = [&](const float* r) {
        union { ushort_t u[8]; int4 v; } pk;
#pragma unroll
        for (int i = 0; i < 8; ++i) pk.u[i] = f2b(r[i]);
        *(int4*)(At + sm * 32 + koff) = pk.v;
    };
    auto buildBt = [&]() {
        union { ushort_t u[8]; int4 v; } pk;
#pragma unroll
        for (int i = 0; i < 8; ++i) pk.u[i] = f2b(Wtmp[(kB8 + i) * 68 + colp]);
        *(int4*)(Bt + nB * 32 + kB8) = pk.v;
    };

    f4v acc[4] = { {0.f,0.f,0.f,0.f}, {0.f,0.f,0.f,0.f},
                   {0.f,0.f,0.f,0.f}, {0.f,0.f,0.f,0.f} };

    // prologue: Wtmp <- W(0); prefetch W(1), A(0), A(1)
    float ac[8], an[8], wn[8];
    loadA(ac, 0);
    {
        float w0r[8];
        loadW(w0r, 0);
        storeWtmp(w0r);
    }
    loadW(wn, 1);
    loadA(an, 1);
    __syncthreads();

    for (int kk = 0; kk < 16; ++kk) {
        // phase1: build At (A tile kk) and Bt (transpose of Wtmp = W tile kk)
        storeAt(ac);
        buildBt();
        __syncthreads();
        // phase2: stage next W tile, issue prefetches, MFMA on current tiles
        if (kk < 15) storeWtmp(wn);          // W tile kk+1 (reads of tile kk done)
        if (kk < 14) loadW(wn, kk + 2);
        if (kk < 15) {
#pragma unroll
            for (int i = 0; i < 8; ++i) ac[i] = an[i];
        }
        if (kk < 14) loadA(an, kk + 2);
        s8v af = *(const s8v*)(At + (wvx * 16 + l16) * 32 + quad * 8);
#pragma unroll
        for (int ng = 0; ng < 4; ++ng) {
            s8v bf = *(const s8v*)(Bt + (ng * 16 + l16) * 32 + quad * 8);
            acc[ng] = __builtin_amdgcn_mfma_f32_16x16x32_bf16(af, bf, acc[ng], 0, 0, 0);
        }
        __syncthreads();
    }

    // epilogue: pre-scale by 2*log2e so k2 can use exp2 directly.
#pragma unroll
    for (int ng = 0; ng < 4; ++ng) {
        int col = n0 + ng * 16 + l16;
        float bb = bias ? bias[col] : 0.f;
#pragma unroll
        for (int rr2 = 0; rr2 < 4; ++rr2) {
            int row = m0 + wvx * 16 + quad * 4 + rr2;
            if (row < M) C[row * D_ + col] = (acc[ng][rr2] + bb) * C2L2E;
        }
    }
}

// ---------------- k2: additive-attention scores — 5 wave-fifths per job ----------------
// 5280 blocks x 4 waves = 21120 wave-fifths (R7, proven). Masked jobs exit.
// score = Vsum - 2*sum_d v[d]*sigmoid(-2x); exp(2x)=exp2(pre-scaled sum).
__global__ __launch_bounds__(256) void k2_scores(
    const float* __restrict__ v_word, const float* __restrict__ v_sent,
    const float* __restrict__ v_pass,
    const int* __restrict__ src_lengths, const int* __restrict__ qa_word_lengths,
    float* __restrict__ wsf)
{
    int lane = threadIdx.x & 63;
    int jid = blockIdx.x * 4 + (threadIdx.x >> 6);   // 21120 wave-fifths, exact
    int job = jid / 5, fifth = jid - job * 5;
    int b = job / NJOB_, slot = job - b * NJOB_;
    const float* uh; const float* v; const float* wq; float* out; int ostride;
    if (slot < SRC_) {
        if (slot >= src_lengths[b]) return;           // masked: value never read
        uh = wsf + OFF_UH_SRC + (size_t)(b * SRC_ + slot) * D_;
        v = v_pass; wq = wsf + OFF_WQ_PASS + b * T_ * D_;
        out = wsf + OFF_SC_SRC + b * T_ * SRC_ + slot; ostride = SRC_;
    } else if (slot < NMEM_) {
        int j = slot - SRC_;
        int se = j / WORDS_; int wd = j - se * WORDS_;
        if (wd >= qa_word_lengths[b * SENTS_ + se]) return;  // masked
        uh = wsf + OFF_UH_WORD + (size_t)(b * NW_ + j) * D_;
        v = v_word; wq = wsf + OFF_WQ_WORD + b * T_ * D_;
        out = wsf + OFF_SC_WORD + b * T_ * NW_ + j; ostride = NW_;
    } else {
        int s2 = slot - NMEM_;
        uh = wsf + OFF_UH_SENT + (size_t)(b * SENTS_ + s2) * D_;
        v = v_sent; wq = wsf + OFF_WQ_SENT + b * T_ * D_;
        out = wsf + OFF_SC_SENT + b * T_ * SENTS_ + s2; ostride = SENTS_;
    }
    int d0 = lane * 8;
    float4 u0 = *(const float4*)(uh + d0);
    float4 u1 = *(const float4*)(uh + d0 + 4);
    float uhr[8] = {u0.x, u0.y, u0.z, u0.w, u1.x, u1.y, u1.z, u1.w};
    float4 v0 = *(const float4*)(v + d0);
    float4 v1 = *(const float4*)(v + d0 + 4);
    float vr[8] = {v0.x, v0.y, v0.z, v0.w, v1.x, v1.y, v1.z, v1.w};

    // Vsum = sum_d v[d] (broadcast to all lanes)
    float vs = ((vr[0] + vr[1]) + (vr[2] + vr[3])) + ((vr[4] + vr[5]) + (vr[6] + vr[7]));
#pragma unroll
    for (int off = 32; off > 0; off >>= 1) vs += __shfl_xor(vs, off, 64);

    const float* wqh = wq + (fifth * 10) * D_ + d0;
    int tbase = fifth * 10;
#pragma unroll 1
    for (int g = 0; g < 2; ++g) {
        float a5[5];
#pragma unroll
        for (int u5 = 0; u5 < 5; ++u5) {
            const float* wr = wqh + (g * 5 + u5) * D_;
            float4 w0 = *(const float4*)(wr);
            float4 w1 = *(const float4*)(wr + 4);
            float wrr[8] = {w0.x, w0.y, w0.z, w0.w, w1.x, w1.y, w1.z, w1.w};
            float a = 0.f;
#pragma unroll
            for (int j = 0; j < 8; ++j) {
                float e = __builtin_amdgcn_exp2f(wrr[j] + uhr[j]);  // exp(2x)
                float r = __builtin_amdgcn_rcpf(e + 1.f);           // sigmoid(-2x)
                a = fmaf(vr[j], r, a);
            }
            a5[u5] = a;
        }
        // 5 interleaved butterfly reductions (all indices static -> registers)
#pragma unroll
        for (int off = 32; off > 0; off >>= 1) {
#pragma unroll
            for (int u5 = 0; u5 < 5; ++u5) a5[u5] += __shfl_xor(a5[u5], off, 64);
        }
        if (lane == 0) {
#pragma unroll
            for (int u5 = 0; u5 < 5; ++u5)
                out[(tbase + g * 5 + u5) * ostride] = fmaf(-2.f, a5[u5], vs);
        }
    }
}

// ---------------- k3a: hier combine + mask + softmax -> bf16 P[b][64][1056] ----------------
__global__ __launch_bounds__(256) void k3a_softmax(
    const int* __restrict__ src_lengths, const int* __restrict__ qa_word_lengths,
    const float* __restrict__ wsf, ushort_t* __restrict__ P)
{
    __shared__ float p[NMEM_];
    __shared__ float red[4];
    int tid = threadIdx.x, lane = tid & 63, wv = tid >> 6;
    int bt = blockIdx.x, b = bt / T_, t = bt - b * T_;
    const float* sc_src  = wsf + OFF_SC_SRC  + bt * SRC_;
    const float* sc_word = wsf + OFF_SC_WORD + bt * NW_;
    const float* sc_sent = wsf + OFF_SC_SENT + bt * SENTS_;
    int slen = src_lengths[b];
    float mx = -3.0e38f;
    for (int j = tid; j < NMEM_; j += 256) {
        float val;
        if (j < SRC_) {
            val = (j < slen) ? sc_src[j] : -1e30f;
        } else {
            int jj = j - SRC_; int se = jj / WORDS_; int wd = jj - se * WORDS_;
            float raw = sc_word[jj] * sc_sent[se];
            val = (wd < qa_word_lengths[b * SENTS_ + se]) ? raw : -1e30f;
        }
        p[j] = val;
        mx = fmaxf(mx, val);
    }
#pragma unroll
    for (int off = 32; off > 0; off >>= 1) mx = fmaxf(mx, __shfl_xor(mx, off, 64));
    if (lane == 0) red[wv] = mx;
    __syncthreads();
    mx = fmaxf(fmaxf(red[0], red[1]), fmaxf(red[2], red[3]));
    __syncthreads();
    float lsum = 0.f;
    for (int j = tid; j < NMEM_; j += 256) {
        float e = __expf(p[j] - mx);
        p[j] = e; lsum += e;
    }
#pragma unroll
    for (int off = 32; off > 0; off >>= 1) lsum += __shfl_xor(lsum, off, 64);
    if (lane == 0) red[wv] = lsum;
    __syncthreads();
    float inv = 1.f / (red[0] + red[1] + red[2] + red[3]);
    ushort_t* prow = P + (size_t)(b * 64 + t) * NK_;
    for (int j = tid; j < NK_; j += 256)
        prow[j] = (j < NMEM_) ? f2b(p[j] * inv) : (ushort_t)0;
}

// ---------------- k3c: context GEMM  C[b][t][d] = sum_s P[t,s] * Mt[d,s] ----------------
// grid (16 d-tiles, 4 b), 256 thr. Tile 64(t,pad) x 32(d), K=1056.
// Depth-3 register prefetch of P (int4) and Mt (int2).
__global__ __launch_bounds__(256) void k3c_gemm(
    const ushort_t* __restrict__ P, const ushort_t* __restrict__ Mt,
    float* __restrict__ out)
{
    __shared__ short At[64 * 32];
    __shared__ short Bt[32 * 32];
    int b = blockIdx.y;
    int n0 = blockIdx.x * 32;
    int tid = threadIdx.x;
    int lane = tid & 63, wv = tid >> 6;
    int quad = lane >> 4, l16 = lane & 15;
    int smA = tid >> 2, koffA = (tid & 3) * 8;   // A: 64 rows x 32k, int4/thread
    int smB = tid >> 3, koffB = (tid & 7) * 4;   // B: 32 rows x 32k, int2/thread

    const ushort_t* arow = P + (size_t)(b * 64 + smA) * NK_ + koffA;
    const ushort_t* brow = Mt + ((size_t)(b * D_ + n0 + smB)) * NK_ + koffB;

    f4v acc[2] = { {0.f,0.f,0.f,0.f}, {0.f,0.f,0.f,0.f} };

    // depth-3 prefetch pipeline
    int4 a0 = *(const int4*)(arow);
    int2 b0 = *(const int2*)(brow);
    int4 a1 = *(const int4*)(arow + 32);
    int2 b1 = *(const int2*)(brow + 32);
    int4 a2 = *(const int4*)(arow + 64);
    int2 b2 = *(const int2*)(brow + 64);

    for (int kk = 0; kk < 33; ++kk) {
        *(int4*)(At + smA * 32 + koffA) = a0;
        *(int2*)(Bt + smB * 32 + koffB) = b0;
        __syncthreads();
        a0 = a1; a1 = a2; b0 = b1; b1 = b2;
        if (kk < 30) {
            a2 = *(const int4*)(arow + (kk + 3) * 32);
            b2 = *(const int2*)(brow + (kk + 3) * 32);
        }
        s8v af = *(const s8v*)(At + (wv * 16 + l16) * 32 + quad * 8);
#pragma unroll
        for (int ng = 0; ng < 2; ++ng) {
            s8v bf = *(const s8v*)(Bt + (ng * 16 + l16) * 32 + quad * 8);
            acc[ng] = __builtin_amdgcn_mfma_f32_16x16x32_bf16(af, bf, acc[ng], 0, 0, 0);
        }
        __syncthreads();
    }
#pragma unroll
    for (int ng = 0; ng < 2; ++ng) {
        int col = n0 + ng * 16 + l16;
#pragma unroll
        for (int rr = 0; rr < 4; ++rr) {
            int row = wv * 16 + quad * 4 + rr;   // t
            if (row < T_) out[(size_t)(b * T_ + row) * D_ + col] = acc[ng][rr];
        }
    }
}

extern "C" void kernel_launch(void* const* d_in, const int* in_sizes, int n_in,
                              void* d_out, int out_size, void* d_ws, size_t ws_size,
                              hipStream_t stream)
{
    (void)in_sizes; (void)n_in; (void)out_size; (void)ws_size;
    const float* source          = (const float*)d_in[0];
    const float* src_bank        = (const float*)d_in[1];
    const int*   src_lengths     = (const int*)d_in[2];
    const float* qa_sent_bank    = (const float*)d_in[3];
    /* d_in[4] qa_sent_lengths unused (matches reference) */
    const float* qa_word_bank    = (const float*)d_in[5];
    const int*   qa_word_lengths = (const int*)d_in[6];
    const float* Wq_word = (const float*)d_in[7];
    const float* bq_word = (const float*)d_in[8];
    const float* Uc_word = (const float*)d_in[9];
    const float* v_word  = (const float*)d_in[10];
    const float* Wq_sent = (const float*)d_in[11];
    const float* bq_sent = (const float*)d_in[12];
    const float* Uc_sent = (const float*)d_in[13];
    const float* v_sent  = (const float*)d_in[14];
    const float* Wq_pass = (const float*)d_in[15];
    const float* bq_pass = (const float*)d_in[16];
    const float* Uc_pass = (const float*)d_in[17];
    const float* v_pass  = (const float*)d_in[18];

    float* wsf = (float*)d_ws;
    ushort_t* Pb  = (ushort_t*)((char*)d_ws + P_BYTE_OFF);
    ushort_t* mt  = (ushort_t*)((char*)d_ws + MT_BYTE_OFF);
    float* out = (float*)d_out;

    // W order must match kA segment order:
    // 0:Wq_word 1:Wq_sent 2:Wq_pass 3:Uc_word 4:Uc_pass 5:Uc_sent
    // grid: 624 GEMM blocks + 2112 bank-transpose blocks = 2736
    kA<<<dim3(2736), dim3(256), 0, stream>>>(
        source, src_bank, qa_sent_bank, qa_word_bank,
        Wq_word, Wq_sent, Wq_pass, Uc_word, Uc_pass, Uc_sent,
        bq_word, bq_sent, bq_pass, wsf, mt);
    k2_scores<<<dim3(5280), dim3(256), 0, stream>>>(
        v_word, v_sent, v_pass, src_lengths, qa_word_lengths, wsf);
    k3a_softmax<<<dim3(200), dim3(256), 0, stream>>>(src_lengths, qa_word_lengths, wsf, Pb);
    k3c_gemm<<<dim3(16, 4), dim3(256), 0, stream>>>(Pb, mt, out);
}